// Round 6
// baseline (547.824 us; speedup 1.0000x reference)
//
#include <hip/hip_runtime.h>

// ---------------- problem constants ----------------
#define B_DIM   8
#define NPTS    81920
#define DTOT    20          // DL(16) + DA(4)
#define DT_STEP 0.1f

// ---------------- kernel geometry ----------------
#define BLOCK 64            // 1 wave/block
#define GRID  5120          // (GRID/8) * ITERS * 16 = 81920 points per batch
#define ITERS 8             // 2x r5: amortize startup, deeper pipeline
#define MROW  40            // mirror row bytes (20 bf16)
#define NFRAG 21
#define SMEM_BYTES 8704     // double-buffered hrow: 2 x 16 rows x 272 B
#define FIMG_BYTES 32768
#define TANH_SCALE 2.885390082f   // 2*log2(e), folded into baked W1/b1

typedef __attribute__((ext_vector_type(8))) short    short8;   // 8 bf16
typedef __attribute__((ext_vector_type(4))) float    f32x4;
typedef __attribute__((ext_vector_type(2))) unsigned u32x2;
typedef __attribute__((ext_vector_type(4))) unsigned u32x4;
typedef __attribute__((ext_vector_type(2))) short    short2v;

__device__ __forceinline__ unsigned short f2bf(float f) {
    unsigned u = __builtin_bit_cast(unsigned, f);
    u += 0x7FFFu + ((u >> 16) & 1u);           // RNE
    return (unsigned short)(u >> 16);
}
#if __has_builtin(__builtin_amdgcn_cvt_pk_bf16_f32)
__device__ __forceinline__ unsigned pack2(float a, float b) {
    short2v p = __builtin_amdgcn_cvt_pk_bf16_f32(a, b);
    return __builtin_bit_cast(unsigned, p);
}
#else
__device__ __forceinline__ unsigned pack2(float a, float b) {
    return (unsigned)f2bf(a) | ((unsigned)f2bf(b) << 16);
}
#endif
// tanh with the 2*log2(e) scale pre-folded into W1/b1:
// tanh(x) = 1 - 2/(exp2(a)+1) where a = x*2*log2e comes out of the MFMA.
__device__ __forceinline__ float tanh_folded(float a) {
    float e = __builtin_amdgcn_exp2f(a);
    float r = __builtin_amdgcn_rcpf(1.0f + e);
    return 1.0f - 2.0f * r;
}

// k-slot (ks,q,j) -> feature index (0..59), 60 = bias, 61 = zero pad.
// (Hardware-verified correct in rounds 2-5.)
__device__ __forceinline__ int feat_of(int ks, int q, int j) {
    if (ks == 0) {
        if (q == 0) return j;                       // r0 f0-7
        if (q == 1) return 8 + j;                   // r0 f8-15
        if (q == 2) return 20 + j;                  // r1 f0-7
        return (j < 4) ? 16 + j : 36 + (j - 4);     // r0 tail | r1 tail
    }
    if (q == 0) return 28 + j;                      // r1 f8-15
    if (q == 1) return 40 + j;                      // r2 f0-7
    if (q == 2) return 48 + j;                      // r2 f8-15
    if (j < 4) return 56 + j;                       // r2 tail
    return (j == 4) ? 60 : 61;                      // bias | zero
}

// ---- dispatch 1: bf16 mirror build (M0 full; DA also into M1 and out,
// written ONCE — steps never touch DA again) + fragment bake in block 0 ----
__global__ __launch_bounds__(256) void build_mirror(
    const f32x4* __restrict__ in, u32x2* __restrict__ m0,
    u32x2* __restrict__ m1, f32x4* __restrict__ outF, int n4,
    const float* __restrict__ W1, const float* __restrict__ b1,
    const float* __restrict__ W2, const float* __restrict__ b2,
    char* __restrict__ img)
{
    const int i = blockIdx.x * 256 + threadIdx.x;
    if (i < n4) {
        f32x4 v = in[i];
        u32x2 o; o.x = pack2(v.x, v.y); o.y = pack2(v.z, v.w);
        m0[i] = o;
        if ((i % 5) == 4) {          // DA quarter of this row: bake everywhere
            m1[i] = o;
            outF[i] = v;
        }
    }
    if (blockIdx.x == 0) {           // fragment bake (tiny, uniform branch)
        const int t = threadIdx.x, lane = t & 63, g = t >> 6;
        const int l15 = lane & 15, q = lane >> 4;
        for (int f = g; f < NFRAG; f += 4) {
            char* dst = img + (f * 64 + lane) * 16;
            if (f < 16) {                       // B1f[nt][ks]: A[m=nt*16+l15][k]
                const int nt = f >> 1, ks = f & 1, m = nt * 16 + l15;
                unsigned short v[8];
                #pragma unroll
                for (int j = 0; j < 8; j++) {
                    const int ft = feat_of(ks, q, j);
                    float x = (ft < 60) ? TANH_SCALE * W1[ft * 128 + m]
                                        : (ft == 60 ? TANH_SCALE * b1[m] : 0.0f);
                    v[j] = f2bf(x);
                }
                *(u32x4*)dst = *(const u32x4*)v;
            } else if (f < 20) {                // W2f[ks]: pre-scaled by DT
                const int ks = f - 16;
                unsigned short v[8];
                #pragma unroll
                for (int j = 0; j < 8; j++) {
                    const int k = ks * 32 + q * 8 + j;
                    v[j] = f2bf(DT_STEP * W2[k * 16 + l15]);
                }
                *(u32x4*)dst = *(const u32x4*)v;
            } else {                            // acc2init: DT*b2[q*4+r]
                f32x4 a = { DT_STEP * b2[q * 4 + 0], DT_STEP * b2[q * 4 + 1],
                            DT_STEP * b2[q * 4 + 2], DT_STEP * b2[q * 4 + 3] };
                *(f32x4*)dst = a;
            }
        }
    }
}

// wide gather: 2x16B (+1x8B on q==3). q==3's 16B loads over-read 8B past the
// 40B row; lands inside workspace (M0/M1/frag image) and is discarded -> safe.
__device__ __forceinline__ void gather3(
    const char* __restrict__ MinB, int nx0, int nx1, int nx2,
    int offA, int offB, bool selA, bool selB, bool q3,
    u32x4& A, u32x4& Bv, u32x2& C)
{
    const int iA = selA ? nx1 : nx0;          // [r0,r0,r1,r0]
    const int iB = selB ? nx2 : nx1;          // [r1,r2,r2,r1]
    A  = *(const u32x4*)(MinB + (size_t)iA * MROW + offA);
    Bv = *(const u32x4*)(MinB + (size_t)iB * MROW + offB);
    u32x2 c = { 0u, 0u };
    if (q3) c = *(const u32x2*)(MinB + (size_t)nx2 * MROW + 32);
    C = c;
}

// ---- one Euler step. Depth-2 software pipeline: two iterations of gather +
// own-row VMEM in flight per wave (r5 depth-1 left the wave with ~1 iter of
// MLP); nbr indices 4 ahead; hrow double-buffered. ----
__global__ __launch_bounds__(BLOCK, 4) void neural_step(
    const float* __restrict__ Yin, float* __restrict__ Yout,
    const unsigned short* __restrict__ Min,
    unsigned short* __restrict__ Mout,
    const int* __restrict__ nbr, const char* __restrict__ img,
    const int inStride, const int outStride, const int writeMirror)
{
    __shared__ __align__(16) char smem[SMEM_BYTES];
    const int t = threadIdx.x, lane = t & 63;
    const int l15 = lane & 15, q = lane >> 4;
    const bool q3 = (q == 3);
    const bool selA = (q == 2), selB = (q == 1) || (q == 2);
    const int offA = (q == 1) ? 16 : (q3 ? 32 : 0);    // [0,16,0,32]
    const int offB = (q == 1) ? 0  : (q3 ? 32 : 16);   // [16,0,16,32]

    const int bk = blockIdx.x;
    const int bB = bk & 7;                 // batch <-> XCD (perf heuristic only)
    const int p0 = (bk >> 3) * (ITERS * 16) + l15;   // 16 points per iter
    const size_t rowBase = (size_t)bB * NPTS;
    const char*  MinB  = (const char*)Min + (size_t)bB * NPTS * MROW;
    char*        MoutB = (char*)Mout      + (size_t)bB * NPTS * MROW;

    // ---- pipeline state: gathers/own depth 2, nbr depth 4 ----
    u32x4 gA0, gB0, gA1, gB1, gA2 = {0,0,0,0}, gB2 = {0,0,0,0};
    u32x2 gC0, gC1, gC2 = {0,0};
    f32x4 own0, own1, own2 = {0.f, 0.f, 0.f, 0.f};
    int nxA0, nxA1, nxA2;          // nbr for gather issued this iter (it+2)
    int nxB0 = 0, nxB1 = 0, nxB2 = 0;   // nbr for next iter's issue (it+3)

    // prologue: iters 0,1 loads + nbr(2),nbr(3) in flight BEFORE frag loads
    {
        const int* np0 = nbr + (size_t)p0 * 3;
        int a0 = np0[0], a1 = np0[1], a2 = np0[2];
        gather3(MinB, a0, a1, a2, offA, offB, selA, selB, q3, gA0, gB0, gC0);
        own0 = __builtin_nontemporal_load(
            (const f32x4*)(Yin + (rowBase + p0) * inStride) + q);
        const int* np1 = nbr + (size_t)(p0 + 16) * 3;
        int b0 = np1[0], b1i = np1[1], b2i = np1[2];
        gather3(MinB, b0, b1i, b2i, offA, offB, selA, selB, q3, gA1, gB1, gC1);
        own1 = __builtin_nontemporal_load(
            (const f32x4*)(Yin + (rowBase + p0 + 16) * inStride) + q);
        const int* np2 = nbr + (size_t)(p0 + 32) * 3;
        nxA0 = np2[0]; nxA1 = np2[1]; nxA2 = np2[2];
        const int* np3 = nbr + (size_t)(p0 + 48) * 3;
        nxB0 = np3[0]; nxB1 = np3[1]; nxB2 = np3[2];
    }

    // weight fragments: 21 coalesced dwordx4 loads (L2-resident broadcast)
    const short8* frg = (const short8*)img;
    short8 B1f[8][2];
    #pragma unroll
    for (int nt = 0; nt < 8; nt++)
        #pragma unroll
        for (int ks = 0; ks < 2; ks++)
            B1f[nt][ks] = frg[(nt * 2 + ks) * 64 + lane];
    short8 W2f[4];
    #pragma unroll
    for (int ks = 0; ks < 4; ks++)
        W2f[ks] = frg[(16 + ks) * 64 + lane];
    const f32x4 acc2init = ((const f32x4*)img)[20 * 64 + lane];

    #pragma unroll
    for (int it = 0; it < ITERS; it++) {
        // hrow double-buffer: compile-time select (full unroll => static)
        unsigned short* hrow = (unsigned short*)(smem + (it & 1) * 4352);

        // ---- keep 2 iterations of VMEM in flight ----
        if (it + 2 < ITERS) {
            gather3(MinB, nxA0, nxA1, nxA2, offA, offB, selA, selB, q3,
                    gA2, gB2, gC2);
            own2 = __builtin_nontemporal_load(
                (const f32x4*)(Yin + (rowBase + p0 + (it + 2) * 16) * inStride) + q);
        }
        if (it + 4 < ITERS) {
            const int* np = nbr + (size_t)(p0 + (it + 4) * 16) * 3;
            nxA0 = nxB0; nxA1 = nxB1; nxA2 = nxB2;
            nxB0 = np[0]; nxB1 = np[1]; nxB2 = np[2];
        } else {
            nxA0 = nxB0; nxA1 = nxB1; nxA2 = nxB2;
        }

        // assemble permuted B-fragments (q<3: straight 16B pieces;
        // q==3: two row-tails | r2 tail + folded bias {1,0,0,0})
        u32x4 u0 = { gA0.x, gA0.y, q3 ? gB0.x : gA0.z, q3 ? gB0.y : gA0.w };
        u32x4 u1 = { q3 ? gC0.x : gB0.x, q3 ? gC0.y : gB0.y,
                     q3 ? 0x00003F80u : gB0.z, q3 ? 0u : gB0.w };
        short8 zb0 = __builtin_bit_cast(short8, u0);
        short8 zb1 = __builtin_bit_cast(short8, u1);

        // ---- layer 1: D[hidden][point] = (s*W1)^T x Zf^T (+s*b1 fold) ----
        #pragma unroll
        for (int nt = 0; nt < 8; nt++) {
            f32x4 acc = { 0.f, 0.f, 0.f, 0.f };
            acc = __builtin_amdgcn_mfma_f32_16x16x32_bf16(B1f[nt][0], zb0, acc, 0, 0, 0);
            acc = __builtin_amdgcn_mfma_f32_16x16x32_bf16(B1f[nt][1], zb1, acc, 0, 0, 0);
            u32x2 hw;
            hw.x = pack2(tanh_folded(acc[0]), tanh_folded(acc[1]));
            hw.y = pack2(tanh_folded(acc[2]), tanh_folded(acc[3]));
            *(u32x2*)((char*)hrow + l15 * 272 + nt * 32 + q * 8) = hw;
        }

        // ---- layer 2: E[d][point] = (DT*W2)^T x h^T ----
        f32x4 acc2 = acc2init;
        #pragma unroll
        for (int ks = 0; ks < 4; ks++) {
            short8 hb = *(const short8*)((const char*)hrow + l15 * 272 + ks * 64 + q * 16);
            acc2 = __builtin_amdgcn_mfma_f32_16x16x32_bf16(W2f[ks], hb, acc2, 0, 0, 0);
        }

        // ---- epilogue: lane owns point's channels q*4..q*4+3 ----
        const size_t row = rowBase + (size_t)(p0 + it * 16);
        f32x4 o = own0;
        o.x += acc2[0]; o.y += acc2[1]; o.z += acc2[2]; o.w += acc2[3];
        *((f32x4*)(Yout + row * outStride) + q) = o;
        if (writeMirror) {
            char* mrow = MoutB + (size_t)(p0 + it * 16) * MROW;
            u32x2 mw; mw.x = pack2(o.x, o.y); mw.y = pack2(o.z, o.w);
            *(u32x2*)(mrow + q * 8) = mw;
        }

        // rotate pipeline
        own0 = own1; own1 = own2;
        gA0 = gA1; gB0 = gB1; gC0 = gC1;
        gA1 = gA2; gB1 = gB2; gC1 = gC2;
    }
}

extern "C" void kernel_launch(void* const* d_in, const int* in_sizes, int n_in,
                              void* d_out, int out_size, void* d_ws, size_t ws_size,
                              hipStream_t stream) {
    const float* inputs = (const float*)d_in[0];
    const int*   nbr    = (const int*)  d_in[1];
    const float* W1     = (const float*)d_in[2];
    const float* b1     = (const float*)d_in[3];
    const float* W2     = (const float*)d_in[4];
    const float* b2     = (const float*)d_in[5];
    float* out = (float*)d_out;

    const size_t MBYTES = (size_t)B_DIM * NPTS * MROW;      // 26.2 MB each
    const size_t PBYTES = (size_t)B_DIM * NPTS * 16 * 4;    // 41.9 MB packed DL
    unsigned short* M0 = (unsigned short*)d_ws;
    unsigned short* M1 = (unsigned short*)((char*)d_ws + MBYTES);
    char*           FI = (char*)d_ws + 2 * MBYTES;
    float*          P  = (float*)(FI + FIMG_BYTES);

    // packed DL scratch only if the workspace is big enough (safe fallback)
    const bool usePacked = ws_size >= 2 * MBYTES + FIMG_BYTES + PBYTES;
    float* mid  = usePacked ? P : out;
    const int sMid = usePacked ? 16 : DTOT;

    const int n4 = B_DIM * NPTS * DTOT / 4;                 // 3,276,800
    build_mirror<<<n4 / 256, 256, 0, stream>>>(
        (const f32x4*)inputs, (u32x2*)M0, (u32x2*)M1, (f32x4*)out, n4,
        W1, b1, W2, b2, FI);

    const dim3 grid(GRID), block(BLOCK);
    neural_step<<<grid, block, 0, stream>>>(inputs, mid, M0, M1, nbr, FI,
                                            DTOT, sMid, 1);
    neural_step<<<grid, block, 0, stream>>>(mid, mid, M1, M0, nbr, FI,
                                            sMid, sMid, 1);
    neural_step<<<grid, block, 0, stream>>>(mid, mid, M0, M1, nbr, FI,
                                            sMid, sMid, 1);
    neural_step<<<grid, block, 0, stream>>>(mid, out, M1, M0, nbr, FI,
                                            sMid, DTOT, 0);
}

// Round 7
// 283.974 us; speedup vs baseline: 1.9291x; 1.9291x over previous
//
#include <hip/hip_runtime.h>

// ---------------- problem constants ----------------
#define B_DIM   8
#define NPTS    81920
#define DTOT    20          // DL(16) + DA(4)
#define DT_STEP 0.1f

// ---------------- kernel geometry ----------------
#define BLOCK 64            // 1 wave/block
#define GRID  5120          // (GRID/8) * ITERS * 16 = 81920 points per batch
#define ITERS 8             // startup amortization (depth-1 pipeline, r5-safe)
#define MROW  40            // mirror row bytes (20 bf16)
#define NFRAG 21
#define SMEM_BYTES 8704     // double-buffered hrow: 2 x 16 rows x 272 B
#define FIMG_BYTES 32768
#define TANH_SCALE 2.885390082f   // 2*log2(e), folded into baked W1/b1

typedef __attribute__((ext_vector_type(8))) short    short8;   // 8 bf16
typedef __attribute__((ext_vector_type(4))) float    f32x4;
typedef __attribute__((ext_vector_type(2))) unsigned u32x2;
typedef __attribute__((ext_vector_type(4))) unsigned u32x4;
typedef __attribute__((ext_vector_type(2))) short    short2v;

__device__ __forceinline__ unsigned short f2bf(float f) {
    unsigned u = __builtin_bit_cast(unsigned, f);
    u += 0x7FFFu + ((u >> 16) & 1u);           // RNE
    return (unsigned short)(u >> 16);
}
#if __has_builtin(__builtin_amdgcn_cvt_pk_bf16_f32)
__device__ __forceinline__ unsigned pack2(float a, float b) {
    short2v p = __builtin_amdgcn_cvt_pk_bf16_f32(a, b);
    return __builtin_bit_cast(unsigned, p);
}
#else
__device__ __forceinline__ unsigned pack2(float a, float b) {
    return (unsigned)f2bf(a) | ((unsigned)f2bf(b) << 16);
}
#endif
// tanh with the 2*log2(e) scale pre-folded into W1/b1:
// tanh(x) = 1 - 2/(exp2(a)+1) where a = x*2*log2e comes out of the MFMA.
__device__ __forceinline__ float tanh_folded(float a) {
    float e = __builtin_amdgcn_exp2f(a);
    float r = __builtin_amdgcn_rcpf(1.0f + e);
    return 1.0f - 2.0f * r;
}

// k-slot (ks,q,j) -> feature index (0..59), 60 = bias, 61 = zero pad.
// (Hardware-verified correct in rounds 2-5.)
__device__ __forceinline__ int feat_of(int ks, int q, int j) {
    if (ks == 0) {
        if (q == 0) return j;                       // r0 f0-7
        if (q == 1) return 8 + j;                   // r0 f8-15
        if (q == 2) return 20 + j;                  // r1 f0-7
        return (j < 4) ? 16 + j : 36 + (j - 4);     // r0 tail | r1 tail
    }
    if (q == 0) return 28 + j;                      // r1 f8-15
    if (q == 1) return 40 + j;                      // r2 f0-7
    if (q == 2) return 48 + j;                      // r2 f8-15
    if (j < 4) return 56 + j;                       // r2 tail
    return (j == 4) ? 60 : 61;                      // bias | zero
}

// ---- dispatch 1: bf16 mirror build (M0 full; DA also into M1 and out,
// written ONCE — steps never touch DA again) + fragment bake in block 0 ----
__global__ __launch_bounds__(256) void build_mirror(
    const f32x4* __restrict__ in, u32x2* __restrict__ m0,
    u32x2* __restrict__ m1, f32x4* __restrict__ outF, int n4,
    const float* __restrict__ W1, const float* __restrict__ b1,
    const float* __restrict__ W2, const float* __restrict__ b2,
    char* __restrict__ img)
{
    const int i = blockIdx.x * 256 + threadIdx.x;
    if (i < n4) {
        f32x4 v = in[i];
        u32x2 o; o.x = pack2(v.x, v.y); o.y = pack2(v.z, v.w);
        m0[i] = o;
        if ((i % 5) == 4) {          // DA quarter of this row: bake everywhere
            m1[i] = o;
            outF[i] = v;
        }
    }
    if (blockIdx.x == 0) {           // fragment bake (tiny, uniform branch)
        const int t = threadIdx.x, lane = t & 63, g = t >> 6;
        const int l15 = lane & 15, q = lane >> 4;
        for (int f = g; f < NFRAG; f += 4) {
            char* dst = img + (f * 64 + lane) * 16;
            if (f < 16) {                       // B1f[nt][ks]: A[m=nt*16+l15][k]
                const int nt = f >> 1, ks = f & 1, m = nt * 16 + l15;
                unsigned short v[8];
                #pragma unroll
                for (int j = 0; j < 8; j++) {
                    const int ft = feat_of(ks, q, j);
                    float x = (ft < 60) ? TANH_SCALE * W1[ft * 128 + m]
                                        : (ft == 60 ? TANH_SCALE * b1[m] : 0.0f);
                    v[j] = f2bf(x);
                }
                *(u32x4*)dst = *(const u32x4*)v;
            } else if (f < 20) {                // W2f[ks]: pre-scaled by DT
                const int ks = f - 16;
                unsigned short v[8];
                #pragma unroll
                for (int j = 0; j < 8; j++) {
                    const int k = ks * 32 + q * 8 + j;
                    v[j] = f2bf(DT_STEP * W2[k * 16 + l15]);
                }
                *(u32x4*)dst = *(const u32x4*)v;
            } else {                            // acc2init: DT*b2[q*4+r]
                f32x4 a = { DT_STEP * b2[q * 4 + 0], DT_STEP * b2[q * 4 + 1],
                            DT_STEP * b2[q * 4 + 2], DT_STEP * b2[q * 4 + 3] };
                *(f32x4*)dst = a;
            }
        }
    }
}

// wide gather: 2x16B (+1x8B on q==3). q==3's 16B loads over-read 8B past the
// 40B row; lands inside workspace (M0/M1/frag image) and is discarded -> safe.
__device__ __forceinline__ void gather3(
    const char* __restrict__ MinB, int nx0, int nx1, int nx2,
    int offA, int offB, bool selA, bool selB, bool q3,
    u32x4& A, u32x4& Bv, u32x2& C)
{
    const int iA = selA ? nx1 : nx0;          // [r0,r0,r1,r0]
    const int iB = selB ? nx2 : nx1;          // [r1,r2,r2,r1]
    A  = *(const u32x4*)(MinB + (size_t)iA * MROW + offA);
    Bv = *(const u32x4*)(MinB + (size_t)iB * MROW + offB);
    u32x2 c = { 0u, 0u };
    if (q3) c = *(const u32x2*)(MinB + (size_t)nx2 * MROW + 32);
    C = c;
}

// ---- one Euler step. r5-verified structure: depth-1 software pipeline
// (nbr idx 2 ahead, gather + own-row 1 ahead), hrow double-buffered.
// ITERS=8 amortizes the 21-fragment startup over 2x more work per block.
// NO min-waves launch bound: r6 showed it forces a 64-VGPR clamp + spill. ----
__global__ __launch_bounds__(BLOCK) void neural_step(
    const float* __restrict__ Yin, float* __restrict__ Yout,
    const unsigned short* __restrict__ Min,
    unsigned short* __restrict__ Mout,
    const int* __restrict__ nbr, const char* __restrict__ img,
    const int inStride, const int outStride, const int writeMirror)
{
    __shared__ __align__(16) char smem[SMEM_BYTES];
    const int t = threadIdx.x, lane = t & 63;
    const int l15 = lane & 15, q = lane >> 4;
    const bool q3 = (q == 3);
    const bool selA = (q == 2), selB = (q == 1) || (q == 2);
    const int offA = (q == 1) ? 16 : (q3 ? 32 : 0);    // [0,16,0,32]
    const int offB = (q == 1) ? 0  : (q3 ? 32 : 16);   // [16,0,16,32]

    const int bk = blockIdx.x;
    const int bB = bk & 7;                 // batch <-> XCD (perf heuristic only)
    const int p0 = (bk >> 3) * (ITERS * 16) + l15;   // 16 points per iter
    const size_t rowBase = (size_t)bB * NPTS;
    const char*  MinB  = (const char*)Min + (size_t)bB * NPTS * MROW;
    char*        MoutB = (char*)Mout      + (size_t)bB * NPTS * MROW;

    // ---- prologue loads FIRST: nbr(0,1), gather(0), own(0) in flight
    // before the 21 fragment loads stack on top (overlap startup latency) ----
    int nx0, nx1, nx2, ny0 = 0, ny1 = 0, ny2 = 0;
    u32x4 gA, gB, nA = {0,0,0,0}, nB = {0,0,0,0};
    u32x2 gC, nC = {0,0};
    f32x4 ownC, ownN = {0.f, 0.f, 0.f, 0.f};
    {
        const int* np = nbr + (size_t)p0 * 3;
        nx0 = np[0]; nx1 = np[1]; nx2 = np[2];
        gather3(MinB, nx0, nx1, nx2, offA, offB, selA, selB, q3, gA, gB, gC);
        ownC = __builtin_nontemporal_load(
            (const f32x4*)(Yin + (rowBase + p0) * inStride) + q);
        const int* np1 = nbr + (size_t)(p0 + 16) * 3;
        nx0 = np1[0]; nx1 = np1[1]; nx2 = np1[2];
    }

    // weight fragments: 21 coalesced dwordx4 loads (L2-resident broadcast)
    const short8* frg = (const short8*)img;
    short8 B1f[8][2];
    #pragma unroll
    for (int nt = 0; nt < 8; nt++)
        #pragma unroll
        for (int ks = 0; ks < 2; ks++)
            B1f[nt][ks] = frg[(nt * 2 + ks) * 64 + lane];
    short8 W2f[4];
    #pragma unroll
    for (int ks = 0; ks < 4; ks++)
        W2f[ks] = frg[(16 + ks) * 64 + lane];
    const f32x4 acc2init = ((const f32x4*)img)[20 * 64 + lane];

    #pragma unroll
    for (int it = 0; it < ITERS; it++) {
        // hrow double-buffer: compile-time select (full unroll => static)
        unsigned short* hrow = (unsigned short*)(smem + (it & 1) * 4352);

        // ---- prefetch next iter's own row + gather; it+2's nbr ----
        if (it + 1 < ITERS) {
            ownN = __builtin_nontemporal_load(
                (const f32x4*)(Yin + (rowBase + p0 + (it + 1) * 16) * inStride) + q);
            gather3(MinB, nx0, nx1, nx2, offA, offB, selA, selB, q3,
                    nA, nB, nC);
        }
        if (it + 2 < ITERS) {
            const int* np = nbr + (size_t)(p0 + (it + 2) * 16) * 3;
            ny0 = np[0]; ny1 = np[1]; ny2 = np[2];
        }

        // assemble permuted B-fragments (q<3: straight 16B pieces;
        // q==3: two row-tails | r2 tail + folded bias {1,0,0,0})
        u32x4 u0 = { gA.x, gA.y, q3 ? gB.x : gA.z, q3 ? gB.y : gA.w };
        u32x4 u1 = { q3 ? gC.x : gB.x, q3 ? gC.y : gB.y,
                     q3 ? 0x00003F80u : gB.z, q3 ? 0u : gB.w };
        short8 zb0 = __builtin_bit_cast(short8, u0);
        short8 zb1 = __builtin_bit_cast(short8, u1);

        // ---- layer 1: D[hidden][point] = (s*W1)^T x Zf^T (+s*b1 fold) ----
        #pragma unroll
        for (int nt = 0; nt < 8; nt++) {
            f32x4 acc = { 0.f, 0.f, 0.f, 0.f };
            acc = __builtin_amdgcn_mfma_f32_16x16x32_bf16(B1f[nt][0], zb0, acc, 0, 0, 0);
            acc = __builtin_amdgcn_mfma_f32_16x16x32_bf16(B1f[nt][1], zb1, acc, 0, 0, 0);
            u32x2 hw;
            hw.x = pack2(tanh_folded(acc[0]), tanh_folded(acc[1]));
            hw.y = pack2(tanh_folded(acc[2]), tanh_folded(acc[3]));
            *(u32x2*)((char*)hrow + l15 * 272 + nt * 32 + q * 8) = hw;
        }

        // ---- layer 2: E[d][point] = (DT*W2)^T x h^T ----
        f32x4 acc2 = acc2init;
        #pragma unroll
        for (int ks = 0; ks < 4; ks++) {
            short8 hb = *(const short8*)((const char*)hrow + l15 * 272 + ks * 64 + q * 16);
            acc2 = __builtin_amdgcn_mfma_f32_16x16x32_bf16(W2f[ks], hb, acc2, 0, 0, 0);
        }

        // ---- epilogue: lane owns point's channels q*4..q*4+3 ----
        const size_t row = rowBase + (size_t)(p0 + it * 16);
        f32x4 o = ownC;
        o.x += acc2[0]; o.y += acc2[1]; o.z += acc2[2]; o.w += acc2[3];
        *((f32x4*)(Yout + row * outStride) + q) = o;
        if (writeMirror) {
            char* mrow = MoutB + (size_t)(p0 + it * 16) * MROW;
            u32x2 mw; mw.x = pack2(o.x, o.y); mw.y = pack2(o.z, o.w);
            *(u32x2*)(mrow + q * 8) = mw;
        }

        // rotate pipeline
        ownC = ownN;
        gA = nA; gB = nB; gC = nC;
        nx0 = ny0; nx1 = ny1; nx2 = ny2;
    }
}

extern "C" void kernel_launch(void* const* d_in, const int* in_sizes, int n_in,
                              void* d_out, int out_size, void* d_ws, size_t ws_size,
                              hipStream_t stream) {
    const float* inputs = (const float*)d_in[0];
    const int*   nbr    = (const int*)  d_in[1];
    const float* W1     = (const float*)d_in[2];
    const float* b1     = (const float*)d_in[3];
    const float* W2     = (const float*)d_in[4];
    const float* b2     = (const float*)d_in[5];
    float* out = (float*)d_out;

    const size_t MBYTES = (size_t)B_DIM * NPTS * MROW;      // 26.2 MB each
    const size_t PBYTES = (size_t)B_DIM * NPTS * 16 * 4;    // 41.9 MB packed DL
    unsigned short* M0 = (unsigned short*)d_ws;
    unsigned short* M1 = (unsigned short*)((char*)d_ws + MBYTES);
    char*           FI = (char*)d_ws + 2 * MBYTES;
    float*          P  = (float*)(FI + FIMG_BYTES);

    // packed DL scratch only if the workspace is big enough (safe fallback)
    const bool usePacked = ws_size >= 2 * MBYTES + FIMG_BYTES + PBYTES;
    float* mid  = usePacked ? P : out;
    const int sMid = usePacked ? 16 : DTOT;

    const int n4 = B_DIM * NPTS * DTOT / 4;                 // 3,276,800
    build_mirror<<<n4 / 256, 256, 0, stream>>>(
        (const f32x4*)inputs, (u32x2*)M0, (u32x2*)M1, (f32x4*)out, n4,
        W1, b1, W2, b2, FI);

    const dim3 grid(GRID), block(BLOCK);
    neural_step<<<grid, block, 0, stream>>>(inputs, mid, M0, M1, nbr, FI,
                                            DTOT, sMid, 1);
    neural_step<<<grid, block, 0, stream>>>(mid, mid, M1, M0, nbr, FI,
                                            sMid, sMid, 1);
    neural_step<<<grid, block, 0, stream>>>(mid, mid, M0, M1, nbr, FI,
                                            sMid, sMid, 1);
    neural_step<<<grid, block, 0, stream>>>(mid, out, M1, M0, nbr, FI,
                                            sMid, DTOT, 0);
}